// Round 16
// baseline (353.243 us; speedup 1.0000x reference)
//
#include <hip/hip_runtime.h>

typedef unsigned short u16;
typedef unsigned int u32;
typedef __attribute__((ext_vector_type(8))) u16 u16x8;
typedef __attribute__((ext_vector_type(8))) __bf16 bf16x8;
typedef __attribute__((ext_vector_type(4))) float f32x4;

#define CIN 128
#define NB 4
#define NN 4096
#define KPTS 16
#define COUT 256
#define POSB 65536      // NN*KPTS
#define TOTPOS 262144   // NB*POSB
#define CK 2304         // 9*256

__device__ __forceinline__ float bf2f(u16 u){ return __uint_as_float(((u32)u)<<16); }
__device__ __forceinline__ u16 f2bf(float f){
  u32 u = __float_as_uint(f);
  u32 r = (u + 0x7fffu + ((u>>16)&1u)) >> 16;   // RNE
  return (u16)r;
}

// ---- 1. pack conv_w with the U/V transform:
//   out = Wl@x_i + Wr@(x_j-x_i) = (Wl-Wr)@x_i + Wr@x_j
__global__ void pack_w_kernel(const float* __restrict__ w, u16* __restrict__ wp){
  int t = blockIdx.x*256 + threadIdx.x;
  if (t >= COUT*CK) return;
  int co = t / CK; int r = t - co*CK; int tap = r >> 8; int c = r & 255;
  float v;
  if (c < 128)
    v = w[(co*256 + c)*9 + tap] - w[(co*256 + 128 + c)*9 + tap];
  else
    v = w[(co*256 + c)*9 + tap];
  wp[t] = f2bf(v);
}

// ---- 2. transpose+cast x,y [B][128][4096] f32 -> xt,yt [B][4096][128] bf16
__global__ void transpose_cast_kernel(const float* __restrict__ x, const float* __restrict__ y,
                                      u16* __restrict__ xt, u16* __restrict__ yt){
  __shared__ u16 tile[2][32][65];
  int n0 = blockIdx.x*64, c0 = blockIdx.y*32, b = blockIdx.z;
  int t = threadIdx.x;
  int tn = t & 63, tc = t >> 6;
  #pragma unroll
  for (int i=0;i<8;++i){
    int c = tc*8 + i;
    size_t src = ((size_t)(b*CIN + c0 + c))*NN + n0 + tn;
    tile[0][c][tn] = f2bf(x[src]);
    tile[1][c][tn] = f2bf(y[src]);
  }
  __syncthreads();
  int tcc = t & 31, tnn = t >> 5;
  #pragma unroll
  for (int i=0;i<8;++i){
    int n = tnn*8 + i;
    size_t dst = ((size_t)(b*NN + n0 + n))*CIN + c0 + tcc;
    xt[dst] = tile[0][tcc][n];
    yt[dst] = tile[1][tcc][n];
  }
}

// element offset into a [row][32] bf16 tile with 16B-chunk XOR swizzle (read side)
#define SWZ(row, chunk) (((row)*32) + ((((chunk) ^ (((row)>>1)&3))) << 3))

// ---- 3. fused panel-gather + implicit-GEMM conv (BM=256 x BN=128) + bias + max_k + BN stats
// r9 structure (best measured: single barrier/step, 2-ahead slot rotation) with:
//  - setprio removed (m190: negative on lockstep GEMM structures)
//  - XCD-chunked bijective block swizzle: each XCD gets a contiguous 256-ptile
//    range -> its 2MB xt/yt slice + 1.2MB weights fit the private 4MB L2.
__global__ __launch_bounds__(256, 2) void conv_gemm_kernel(const u16* __restrict__ wp,
    const int* __restrict__ e, const u16* __restrict__ xt, const u16* __restrict__ yt,
    const u16* __restrict__ zrow, const float* __restrict__ bias,
    float* __restrict__ ssum, float* __restrict__ ssq, float* __restrict__ maxout){
  __shared__ u16 als[3*8192];    // A (weights) triple buffer, 256co x 32ch each
  __shared__ u16 pnl[2*6144];    // H panel double buffer, 192 rows x 32ch each

  int bid = blockIdx.x;
  int ptile = ((bid & 7) << 8) | (bid >> 3);     // XCD-chunked, bijective (2048 = 8*256)
  int p0 = ptile * 128;
  int b = p0 >> 16;
  int pib0 = p0 & (POSB-1);
  int nb0 = pib0 >> 4;                           // 8 n's per block

  int t = threadIdx.x;
  int lane = t & 63, wave = t >> 6;
  int wr = wave >> 1, wc = wave & 1;             // wave grid 2x2: 128co x 64pos each
  int l15 = lane & 15, l4 = lane >> 4;

  const u16* xb = xt + ((size_t)b)*NN*CIN;
  const u16* yb = yt + ((size_t)b)*NN*CIN;

  // A staging geometry: 4 instr/thread, instr i covers rows wave*64+i*16+(lane>>2)
  int rr = wave*64 + (lane>>2);
  int r0 = rr, r1 = rr+16, r2 = rr+32, r3 = rr+48;
  int ch0 = (lane&3) ^ ((r0>>1)&3);
  int ch1 = (lane&3) ^ ((r1>>1)&3);
  int ch2 = (lane&3) ^ ((r2>>1)&3);
  int ch3 = (lane&3) ^ ((r3>>1)&3);
  int wuni = __builtin_amdgcn_readfirstlane(wave);
  int wu  = wuni*2048;          // A-stage wave slice (elems)
  int wu2 = wuni*512;           // panel-stage wave slice (elems)
  const u16* pA0 = wp + (size_t)r0*CK + ch0*8;
  const u16* pA1 = wp + (size_t)r1*CK + ch1*8;
  const u16* pA2 = wp + (size_t)r2*CK + ch2*8;
  const u16* pA3 = wp + (size_t)r3*CK + ch3*8;

  // panel gather pointers (once per block, 3 rows/thread)
  const u16 *xp[3], *yp[3];
  { int tq4 = t >> 2;
    #pragma unroll
    for (int i=0;i<3;++i){
      int row = i*64 + tq4;                      // 0..191
      int lc = (t&3) ^ ((row>>1)&3);
      int q = (row*57) >> 10;                    // row/18
      int kk = row - q*18 - 1;                   // -1..16
      int n2 = nb0 - 1 + q;
      bool valid = (row < 180) && ((unsigned)n2 < (unsigned)NN) && ((unsigned)kk < (unsigned)KPTS);
      int j0 = 0, j1 = 0;
      if (valid){ int eo = b*POSB + n2*16 + kk; j0 = e[eo]; j1 = e[TOTPOS + eo]; }
      xp[i] = (valid ? xb + (size_t)j1*CIN : zrow) + lc*8;
      yp[i] = (valid ? yb + (size_t)j0*CIN : zrow) + lc*8;
    }
  }

  auto G16 = [&](const u16* g, const u16* l){
    __builtin_amdgcn_global_load_lds((const __attribute__((address_space(1))) u32*)g,
                                     (__attribute__((address_space(3))) u32*)l, 16, 0, 0);
  };

  f32x4 acc[8][4];
  #pragma unroll
  for (int i=0;i<8;++i)
    #pragma unroll
    for (int j=0;j<4;++j) acc[i][j] = (f32x4){0.f,0.f,0.f,0.f};

  // prologue: P0(3), P1(3), A-tap0(4)->slot0, A-tap1(4)->slot1
  G16(xp[0],    &pnl[wu2]);
  G16(xp[1],    &pnl[2048+wu2]);
  G16(xp[2],    &pnl[4096+wu2]);
  G16(xp[0]+32, &pnl[6144+wu2]);
  G16(xp[1]+32, &pnl[6144+2048+wu2]);
  G16(xp[2]+32, &pnl[6144+4096+wu2]);
  #pragma unroll
  for (int s=0; s<2; ++s){
    G16(pA0+s*256, &als[s*8192+wu]);
    G16(pA1+s*256, &als[s*8192+wu+512]);
    G16(pA2+s*256, &als[s*8192+wu+1024]);
    G16(pA3+s*256, &als[s*8192+wu+1536]);
  }

  int aoff[8];
  #pragma unroll
  for (int f=0; f<8; ++f) aoff[f] = SWZ(wr*128 + f*16 + l15, l4);
  int wc72l15 = wc*72 + l15;

  // STEP: [vmcnt(N); s_barrier][ds_read frags][stage P(tau0) + A(t+2)][MFMA x32]
  // vmcnt: allow only step t-1's issues in flight (4, or 7 when t-1 had tau==0)
  #define STEP(TAU) { \
    if ((TAU)==1) asm volatile("s_waitcnt vmcnt(7)\n\ts_barrier" ::: "memory"); \
    else          asm volatile("s_waitcnt vmcnt(4)\n\ts_barrier" ::: "memory"); \
    bf16x8 af[8], bv[4]; \
    { const int abase = ((TAU)%3)*8192; \
      _Pragma("unroll") \
      for (int f=0; f<8; ++f) af[f] = *(bf16x8*)&als[abase + aoff[f]]; } \
    { const u16* pb = pnl + (c&1)*6144; \
      const int kbc = ((TAU)/3)*18 + ((TAU)%3); \
      _Pragma("unroll") \
      for (int f=0; f<4; ++f){ int r = wc72l15 + kbc + f*18; \
        bv[f] = *(bf16x8*)&pb[r*32 + ((l4 ^ ((r>>1)&3))<<3)]; } } \
    if ((TAU)==0){ int cc=(c+1)&7; int co32=(cc&3)*32; \
      const u16* s0=(cc<4?xp[0]:yp[0])+co32; \
      const u16* s1=(cc<4?xp[1]:yp[1])+co32; \
      const u16* s2=(cc<4?xp[2]:yp[2])+co32; \
      int pd=((c+1)&1)*6144; \
      G16(s0,&pnl[pd+wu2]); G16(s1,&pnl[pd+2048+wu2]); G16(s2,&pnl[pd+4096+wu2]); } \
    { const int chs = (c + (((TAU)>=7)?1:0)) & 7; \
      const int koff = ((((TAU)+2)%9)*256) + (chs<<5); \
      const int sbase = (((TAU)+2)%3)*8192; \
      G16(pA0 + koff, &als[sbase + wu]); \
      G16(pA1 + koff, &als[sbase + wu + 512]); \
      G16(pA2 + koff, &als[sbase + wu + 1024]); \
      G16(pA3 + koff, &als[sbase + wu + 1536]); } \
    _Pragma("unroll") \
    for (int fm=0; fm<8; ++fm) \
      _Pragma("unroll") \
      for (int fn=0; fn<4; ++fn) \
        acc[fm][fn] = __builtin_amdgcn_mfma_f32_16x16x32_bf16(af[fm], bv[fn], acc[fm][fn], 0, 0, 0); \
  }

  for (int c = 0; c < 8; ++c){
    STEP(0) STEP(1) STEP(2) STEP(3) STEP(4) STEP(5) STEP(6) STEP(7) STEP(8)
  }
  #undef STEP

  asm volatile("s_waitcnt vmcnt(0)\n\ts_barrier" ::: "memory");  // drain tail stages before LDS reuse

  // ---- epilogue: bias + max over k (l15) + per-channel sum/sumsq
  float* fs = (float*)&als[0];           // fs[0..256) = sum, fs[256..512) = sumsq
  fs[t] = 0.f; fs[256 + t] = 0.f;
  __syncthreads();

  #pragma unroll
  for (int fm=0; fm<8; ++fm){
    #pragma unroll
    for (int j=0; j<4; ++j){
      int ch = wr*128 + fm*16 + l4*4 + j;          // = global co
      float bv2 = bias[ch];
      float s = 0.f, q = 0.f;
      float mv[4];
      #pragma unroll
      for (int fn=0; fn<4; ++fn){
        float v = acc[fm][fn][j] + bv2;
        s += v; q += v*v; mv[fn] = v;
      }
      #pragma unroll
      for (int o=1; o<16; o<<=1){
        s += __shfl_xor(s, o, 64);
        q += __shfl_xor(q, o, 64);
        #pragma unroll
        for (int fn=0; fn<4; ++fn) mv[fn] = fmaxf(mv[fn], __shfl_xor(mv[fn], o, 64));
      }
      if (l15 == 0){
        atomicAdd(&fs[ch], s);
        atomicAdd(&fs[256 + ch], q);
        size_t rowb = ((size_t)(b*COUT + ch)) << 12;
        #pragma unroll
        for (int fn=0; fn<4; ++fn)
          maxout[rowb + nb0 + wc*4 + fn] = mv[fn];
      }
    }
  }
  __syncthreads();
  atomicAdd(&ssum[t], fs[t]);
  atomicAdd(&ssq[t],  fs[256 + t]);
}

// ---- 4. finalize BN scale/shift
__global__ void finalize_stats_kernel(const float* __restrict__ ssum, const float* __restrict__ ssq,
                                      const float* __restrict__ gamma, const float* __restrict__ beta,
                                      float* __restrict__ scale, float* __restrict__ shift){
  int co = threadIdx.x;
  float inv = 1.0f / (float)TOTPOS;
  float mean = ssum[co]*inv;
  float var = ssq[co]*inv - mean*mean;
  float sc = gamma[co] * rsqrtf(var + 1e-5f);
  scale[co] = sc;
  shift[co] = beta[co] - mean*sc;
}

// ---- 5. in-place BN + ReLU on maxout (valid since scale>0)
__global__ void bn_finish_kernel(float* __restrict__ out, const float* __restrict__ scale,
                                 const float* __restrict__ shift){
  int t = blockIdx.x*256 + threadIdx.x;
  int co = (t >> 12) & 255;
  float v = out[t];
  out[t] = fmaxf(fmaf(scale[co], v, shift[co]), 0.f);
}

extern "C" void kernel_launch(void* const* d_in, const int* in_sizes, int n_in,
                              void* d_out, int out_size, void* d_ws, size_t ws_size,
                              hipStream_t stream){
  const float* x = (const float*)d_in[0];
  const float* y = (const float*)d_in[1];
  const int*   e = (const int*)d_in[2];
  const float* w = (const float*)d_in[3];
  const float* bias = (const float*)d_in[4];
  const float* gamma = (const float*)d_in[5];
  const float* beta  = (const float*)d_in[6];
  float* out = (float*)d_out;

  char* ws = (char*)d_ws;                  // total footprint: ~9.6 MB
  u16*   wp    = (u16*)(ws);               // 1,179,648 B
  float* ssum  = (float*)(ws + 1179648);   // 1 KB
  float* ssq   = (float*)(ws + 1180672);   // 1 KB
  u16*   zrow  = (u16*)(ws + 1181696);     // 1 KB zero row
  float* scale = (float*)(ws + 1182720);   // 1 KB
  float* shift = (float*)(ws + 1183744);   // 1 KB
  u16*   xt    = (u16*)(ws + 1184768);     // 4 MB
  u16*   yt    = (u16*)(ws + 5379072);     // 4 MB  (end: 9,573,376)

  hipMemsetAsync(ssum, 0, 3072, stream);   // zero ssum+ssq+zrow every call (deterministic)

  pack_w_kernel<<<2304, 256, 0, stream>>>(w, wp);
  dim3 tg(NN/64, CIN/32, NB);
  transpose_cast_kernel<<<tg, 256, 0, stream>>>(x, y, xt, yt);
  conv_gemm_kernel<<<2048, 256, 0, stream>>>(wp, e, xt, yt, zrow, bias, ssum, ssq, out);
  finalize_stats_kernel<<<1, COUT, 0, stream>>>(ssum, ssq, gamma, beta, scale, shift);
  bn_finish_kernel<<<out_size/256, 256, 0, stream>>>(out, scale, shift);
}

// Round 17
// 323.449 us; speedup vs baseline: 1.0921x; 1.0921x over previous
//
#include <hip/hip_runtime.h>

typedef unsigned short u16;
typedef unsigned int u32;
typedef __attribute__((ext_vector_type(8))) u16 u16x8;
typedef __attribute__((ext_vector_type(8))) __bf16 bf16x8;
typedef __attribute__((ext_vector_type(4))) float f32x4;

#define CIN 128
#define NB 4
#define NN 4096
#define KPTS 16
#define COUT 256
#define POSB 65536      // NN*KPTS
#define TOTPOS 262144   // NB*POSB
#define CK 2304         // 9*256

__device__ __forceinline__ float bf2f(u16 u){ return __uint_as_float(((u32)u)<<16); }
__device__ __forceinline__ u16 f2bf(float f){
  u32 u = __float_as_uint(f);
  u32 r = (u + 0x7fffu + ((u>>16)&1u)) >> 16;   // RNE
  return (u16)r;
}

// ---- 1. pack conv_w with the U/V transform:
//   out = Wl@x_i + Wr@(x_j-x_i) = (Wl-Wr)@x_i + Wr@x_j
__global__ void pack_w_kernel(const float* __restrict__ w, u16* __restrict__ wp){
  int t = blockIdx.x*256 + threadIdx.x;
  if (t >= COUT*CK) return;
  int co = t / CK; int r = t - co*CK; int tap = r >> 8; int c = r & 255;
  float v;
  if (c < 128)
    v = w[(co*256 + c)*9 + tap] - w[(co*256 + 128 + c)*9 + tap];
  else
    v = w[(co*256 + c)*9 + tap];
  wp[t] = f2bf(v);
}

// ---- 2. transpose+cast x,y [B][128][4096] f32 -> xt,yt [B][4096][128] bf16
__global__ void transpose_cast_kernel(const float* __restrict__ x, const float* __restrict__ y,
                                      u16* __restrict__ xt, u16* __restrict__ yt){
  __shared__ u16 tile[2][32][65];
  int n0 = blockIdx.x*64, c0 = blockIdx.y*32, b = blockIdx.z;
  int t = threadIdx.x;
  int tn = t & 63, tc = t >> 6;
  #pragma unroll
  for (int i=0;i<8;++i){
    int c = tc*8 + i;
    size_t src = ((size_t)(b*CIN + c0 + c))*NN + n0 + tn;
    tile[0][c][tn] = f2bf(x[src]);
    tile[1][c][tn] = f2bf(y[src]);
  }
  __syncthreads();
  int tcc = t & 31, tnn = t >> 5;
  #pragma unroll
  for (int i=0;i<8;++i){
    int n = tnn*8 + i;
    size_t dst = ((size_t)(b*NN + n0 + n))*CIN + c0 + tcc;
    xt[dst] = tile[0][tcc][n];
    yt[dst] = tile[1][tcc][n];
  }
}

// element offset into a [row][32] bf16 tile with 16B-chunk XOR swizzle (read side)
#define SWZ(row, chunk) (((row)*32) + ((((chunk) ^ (((row)>>1)&3))) << 3))

// ---- 3. fused panel-gather + implicit-GEMM conv (BM=256 x BN=128) + bias + max_k + BN stats
// r9 structure VERBATIM (best measured: single barrier/step, 2-ahead slot rotation,
// setprio kept — r16 showed removing it inflates VGPR to the cap and spills) with
// ONE change: XCD-chunked bijective block swizzle (r16 A/B: FETCH 47->39 MB).
__global__ __launch_bounds__(256, 2) void conv_gemm_kernel(const u16* __restrict__ wp,
    const int* __restrict__ e, const u16* __restrict__ xt, const u16* __restrict__ yt,
    const u16* __restrict__ zrow, const float* __restrict__ bias,
    float* __restrict__ ssum, float* __restrict__ ssq, float* __restrict__ maxout){
  __shared__ u16 als[3*8192];    // A (weights) triple buffer, 256co x 32ch each
  __shared__ u16 pnl[2*6144];    // H panel double buffer, 192 rows x 32ch each

  int bid = blockIdx.x;
  int ptile = ((bid & 7) << 8) | (bid >> 3);     // XCD-chunked, bijective (2048 = 8*256)
  int p0 = ptile * 128;
  int b = p0 >> 16;
  int pib0 = p0 & (POSB-1);
  int nb0 = pib0 >> 4;                           // 8 n's per block

  int t = threadIdx.x;
  int lane = t & 63, wave = t >> 6;
  int wr = wave >> 1, wc = wave & 1;             // wave grid 2x2: 128co x 64pos each
  int l15 = lane & 15, l4 = lane >> 4;

  const u16* xb = xt + ((size_t)b)*NN*CIN;
  const u16* yb = yt + ((size_t)b)*NN*CIN;

  // A staging geometry: 4 instr/thread, instr i covers rows wave*64+i*16+(lane>>2)
  int rr = wave*64 + (lane>>2);
  int r0 = rr, r1 = rr+16, r2 = rr+32, r3 = rr+48;
  int ch0 = (lane&3) ^ ((r0>>1)&3);
  int ch1 = (lane&3) ^ ((r1>>1)&3);
  int ch2 = (lane&3) ^ ((r2>>1)&3);
  int ch3 = (lane&3) ^ ((r3>>1)&3);
  int wuni = __builtin_amdgcn_readfirstlane(wave);
  int wu  = wuni*2048;          // A-stage wave slice (elems)
  int wu2 = wuni*512;           // panel-stage wave slice (elems)
  const u16* pA0 = wp + (size_t)r0*CK + ch0*8;
  const u16* pA1 = wp + (size_t)r1*CK + ch1*8;
  const u16* pA2 = wp + (size_t)r2*CK + ch2*8;
  const u16* pA3 = wp + (size_t)r3*CK + ch3*8;

  // panel gather pointers (once per block, 3 rows/thread)
  const u16 *xp[3], *yp[3];
  { int tq4 = t >> 2;
    #pragma unroll
    for (int i=0;i<3;++i){
      int row = i*64 + tq4;                      // 0..191
      int lc = (t&3) ^ ((row>>1)&3);
      int q = (row*57) >> 10;                    // row/18
      int kk = row - q*18 - 1;                   // -1..16
      int n2 = nb0 - 1 + q;
      bool valid = (row < 180) && ((unsigned)n2 < (unsigned)NN) && ((unsigned)kk < (unsigned)KPTS);
      int j0 = 0, j1 = 0;
      if (valid){ int eo = b*POSB + n2*16 + kk; j0 = e[eo]; j1 = e[TOTPOS + eo]; }
      xp[i] = (valid ? xb + (size_t)j1*CIN : zrow) + lc*8;
      yp[i] = (valid ? yb + (size_t)j0*CIN : zrow) + lc*8;
    }
  }

  auto G16 = [&](const u16* g, const u16* l){
    __builtin_amdgcn_global_load_lds((const __attribute__((address_space(1))) u32*)g,
                                     (__attribute__((address_space(3))) u32*)l, 16, 0, 0);
  };

  f32x4 acc[8][4];
  #pragma unroll
  for (int i=0;i<8;++i)
    #pragma unroll
    for (int j=0;j<4;++j) acc[i][j] = (f32x4){0.f,0.f,0.f,0.f};

  // prologue: P0(3), P1(3), A-tap0(4)->slot0, A-tap1(4)->slot1
  G16(xp[0],    &pnl[wu2]);
  G16(xp[1],    &pnl[2048+wu2]);
  G16(xp[2],    &pnl[4096+wu2]);
  G16(xp[0]+32, &pnl[6144+wu2]);
  G16(xp[1]+32, &pnl[6144+2048+wu2]);
  G16(xp[2]+32, &pnl[6144+4096+wu2]);
  #pragma unroll
  for (int s=0; s<2; ++s){
    G16(pA0+s*256, &als[s*8192+wu]);
    G16(pA1+s*256, &als[s*8192+wu+512]);
    G16(pA2+s*256, &als[s*8192+wu+1024]);
    G16(pA3+s*256, &als[s*8192+wu+1536]);
  }

  int aoff[8];
  #pragma unroll
  for (int f=0; f<8; ++f) aoff[f] = SWZ(wr*128 + f*16 + l15, l4);
  int wc72l15 = wc*72 + l15;

  // STEP: [vmcnt(N); s_barrier][ds_read frags][stage P(tau0) + A(t+2)][MFMA x32]
  // vmcnt: allow only step t-1's issues in flight (4, or 7 when t-1 had tau==0)
  #define STEP(TAU) { \
    if ((TAU)==1) asm volatile("s_waitcnt vmcnt(7)\n\ts_barrier" ::: "memory"); \
    else          asm volatile("s_waitcnt vmcnt(4)\n\ts_barrier" ::: "memory"); \
    bf16x8 af[8], bv[4]; \
    { const int abase = ((TAU)%3)*8192; \
      _Pragma("unroll") \
      for (int f=0; f<8; ++f) af[f] = *(bf16x8*)&als[abase + aoff[f]]; } \
    { const u16* pb = pnl + (c&1)*6144; \
      const int kbc = ((TAU)/3)*18 + ((TAU)%3); \
      _Pragma("unroll") \
      for (int f=0; f<4; ++f){ int r = wc72l15 + kbc + f*18; \
        bv[f] = *(bf16x8*)&pb[r*32 + ((l4 ^ ((r>>1)&3))<<3)]; } } \
    if ((TAU)==0){ int cc=(c+1)&7; int co32=(cc&3)*32; \
      const u16* s0=(cc<4?xp[0]:yp[0])+co32; \
      const u16* s1=(cc<4?xp[1]:yp[1])+co32; \
      const u16* s2=(cc<4?xp[2]:yp[2])+co32; \
      int pd=((c+1)&1)*6144; \
      G16(s0,&pnl[pd+wu2]); G16(s1,&pnl[pd+2048+wu2]); G16(s2,&pnl[pd+4096+wu2]); } \
    { const int chs = (c + (((TAU)>=7)?1:0)) & 7; \
      const int koff = ((((TAU)+2)%9)*256) + (chs<<5); \
      const int sbase = (((TAU)+2)%3)*8192; \
      G16(pA0 + koff, &als[sbase + wu]); \
      G16(pA1 + koff, &als[sbase + wu + 512]); \
      G16(pA2 + koff, &als[sbase + wu + 1024]); \
      G16(pA3 + koff, &als[sbase + wu + 1536]); } \
    __builtin_amdgcn_s_setprio(1); \
    _Pragma("unroll") \
    for (int fm=0; fm<8; ++fm) \
      _Pragma("unroll") \
      for (int fn=0; fn<4; ++fn) \
        acc[fm][fn] = __builtin_amdgcn_mfma_f32_16x16x32_bf16(af[fm], bv[fn], acc[fm][fn], 0, 0, 0); \
    __builtin_amdgcn_s_setprio(0); \
  }

  for (int c = 0; c < 8; ++c){
    STEP(0) STEP(1) STEP(2) STEP(3) STEP(4) STEP(5) STEP(6) STEP(7) STEP(8)
  }
  #undef STEP

  asm volatile("s_waitcnt vmcnt(0)\n\ts_barrier" ::: "memory");  // drain tail stages before LDS reuse

  // ---- epilogue: bias + max over k (l15) + per-channel sum/sumsq
  float* fs = (float*)&als[0];           // fs[0..256) = sum, fs[256..512) = sumsq
  fs[t] = 0.f; fs[256 + t] = 0.f;
  __syncthreads();

  #pragma unroll
  for (int fm=0; fm<8; ++fm){
    #pragma unroll
    for (int j=0; j<4; ++j){
      int ch = wr*128 + fm*16 + l4*4 + j;          // = global co
      float bv2 = bias[ch];
      float s = 0.f, q = 0.f;
      float mv[4];
      #pragma unroll
      for (int fn=0; fn<4; ++fn){
        float v = acc[fm][fn][j] + bv2;
        s += v; q += v*v; mv[fn] = v;
      }
      #pragma unroll
      for (int o=1; o<16; o<<=1){
        s += __shfl_xor(s, o, 64);
        q += __shfl_xor(q, o, 64);
        #pragma unroll
        for (int fn=0; fn<4; ++fn) mv[fn] = fmaxf(mv[fn], __shfl_xor(mv[fn], o, 64));
      }
      if (l15 == 0){
        atomicAdd(&fs[ch], s);
        atomicAdd(&fs[256 + ch], q);
        size_t rowb = ((size_t)(b*COUT + ch)) << 12;
        #pragma unroll
        for (int fn=0; fn<4; ++fn)
          maxout[rowb + nb0 + wc*4 + fn] = mv[fn];
      }
    }
  }
  __syncthreads();
  atomicAdd(&ssum[t], fs[t]);
  atomicAdd(&ssq[t],  fs[256 + t]);
}

// ---- 4. finalize BN scale/shift
__global__ void finalize_stats_kernel(const float* __restrict__ ssum, const float* __restrict__ ssq,
                                      const float* __restrict__ gamma, const float* __restrict__ beta,
                                      float* __restrict__ scale, float* __restrict__ shift){
  int co = threadIdx.x;
  float inv = 1.0f / (float)TOTPOS;
  float mean = ssum[co]*inv;
  float var = ssq[co]*inv - mean*mean;
  float sc = gamma[co] * rsqrtf(var + 1e-5f);
  scale[co] = sc;
  shift[co] = beta[co] - mean*sc;
}

// ---- 5. in-place BN + ReLU on maxout (valid since scale>0)
__global__ void bn_finish_kernel(float* __restrict__ out, const float* __restrict__ scale,
                                 const float* __restrict__ shift){
  int t = blockIdx.x*256 + threadIdx.x;
  int co = (t >> 12) & 255;
  float v = out[t];
  out[t] = fmaxf(fmaf(scale[co], v, shift[co]), 0.f);
}

extern "C" void kernel_launch(void* const* d_in, const int* in_sizes, int n_in,
                              void* d_out, int out_size, void* d_ws, size_t ws_size,
                              hipStream_t stream){
  const float* x = (const float*)d_in[0];
  const float* y = (const float*)d_in[1];
  const int*   e = (const int*)d_in[2];
  const float* w = (const float*)d_in[3];
  const float* bias = (const float*)d_in[4];
  const float* gamma = (const float*)d_in[5];
  const float* beta  = (const float*)d_in[6];
  float* out = (float*)d_out;

  char* ws = (char*)d_ws;                  // total footprint: ~9.6 MB
  u16*   wp    = (u16*)(ws);               // 1,179,648 B
  float* ssum  = (float*)(ws + 1179648);   // 1 KB
  float* ssq   = (float*)(ws + 1180672);   // 1 KB
  u16*   zrow  = (u16*)(ws + 1181696);     // 1 KB zero row
  float* scale = (float*)(ws + 1182720);   // 1 KB
  float* shift = (float*)(ws + 1183744);   // 1 KB
  u16*   xt    = (u16*)(ws + 1184768);     // 4 MB
  u16*   yt    = (u16*)(ws + 5379072);     // 4 MB  (end: 9,573,376)

  hipMemsetAsync(ssum, 0, 3072, stream);   // zero ssum+ssq+zrow every call (deterministic)

  pack_w_kernel<<<2304, 256, 0, stream>>>(w, wp);
  dim3 tg(NN/64, CIN/32, NB);
  transpose_cast_kernel<<<tg, 256, 0, stream>>>(x, y, xt, yt);
  conv_gemm_kernel<<<2048, 256, 0, stream>>>(wp, e, xt, yt, zrow, bias, ssum, ssq, out);
  finalize_stats_kernel<<<1, COUT, 0, stream>>>(ssum, ssq, gamma, beta, scale, shift);
  bn_finish_kernel<<<out_size/256, 256, 0, stream>>>(out, scale, shift);
}